// Round 3
// baseline (181.626 us; speedup 1.0000x reference)
//
#include <hip/hip_runtime.h>
#include <hip/hip_bf16.h>

// Attention: out[b,q,v] = softmax_d( Q[q,:]·K[b,d,:] / sqrt(128) ) · V[b,d,v]
// B=32, D=8192, DK=DV=128. fp32 in/out, bf16 MFMA internally.
// R2: back to R0 wave structure (256 thr, 4 waves, VGPR 116 — no spills).
//     Occupancy fix via GRID: NSPLIT 16->32 (1024 WGs = 4 blocks/CU).
//     NSPLIT chosen at launch from ws_size (32 if it fits, else 16).

#define Dseq 8192
#define Dk 128

typedef __attribute__((ext_vector_type(8))) short bf16x8;
typedef __attribute__((ext_vector_type(16))) float f32x16;

__device__ __forceinline__ short f2bf(float x) {
  union { float f; unsigned u; } v; v.f = x;
  return (short)((v.u + 0x7FFFu + ((v.u >> 16) & 1u)) >> 16);  // RNE
}

__device__ __forceinline__ bf16x8 cvt8(float4 a, float4 b) {
  bf16x8 r;
  r[0] = f2bf(a.x); r[1] = f2bf(a.y); r[2] = f2bf(a.z); r[3] = f2bf(a.w);
  r[4] = f2bf(b.x); r[5] = f2bf(b.y); r[6] = f2bf(b.z); r[7] = f2bf(b.w);
  return r;
}

// mfma_f32_32x32x16_bf16 layouts (guide §3, m74/m101 verified):
//  A[32,16]: lane l -> row = l&31, k = (l>>5)*8 + j   (8 contiguous K elems)
//  B[16,32]: lane l -> col = l&31, k = (l>>5)*8 + j
//  C/D     : lane l -> col = l&31, row = (r&3) + 8*(r>>2) + 4*(l>>5)

template <int NSPLIT>
__global__ __launch_bounds__(256, 4) void attn_partial(
    const float* __restrict__ Q, const float* __restrict__ K,
    const float* __restrict__ V, float* __restrict__ ows,
    float* __restrict__ mws, float* __restrict__ lws) {
  constexpr int KEYS_PER_WAVE = Dseq / NSPLIT / 4;   // 64 @32, 128 @16
  constexpr int NTILES = KEYS_PER_WAVE / 32;         // 2 @32, 4 @16
  const int tid = threadIdx.x;
  const int lane = tid & 63;
  const int w = tid >> 6;          // wave id 0..3
  const int c32 = lane & 31;
  const int hi = lane >> 5;
  const int wg = blockIdx.x;       // b * NSPLIT + split
  const int b = wg / NSPLIT;
  const int kb0 = (wg % NSPLIT) * (Dseq / NSPLIT) + w * KEYS_PER_WAVE;

  __shared__ alignas(16) short p_lds[4][32][40];  // per-wave P transpose (+pad)
  __shared__ float o_lds[32][128];
  __shared__ float m_lds[4][32];
  __shared__ float l_lds[4][32];

  const float scale = 0.088388347648318447f;  // 1/sqrt(128)

  // ---- Q A-fragments, resident, prescaled
  bf16x8 qa[8];
  {
    const float* qrow = Q + c32 * Dk + hi * 8;
#pragma unroll
    for (int s = 0; s < 8; ++s) {
      float4 a = *(const float4*)(qrow + s * 16);
      float4 b4 = *(const float4*)(qrow + s * 16 + 4);
      a.x *= scale; a.y *= scale; a.z *= scale; a.w *= scale;
      b4.x *= scale; b4.y *= scale; b4.z *= scale; b4.w *= scale;
      qa[s] = cvt8(a, b4);
    }
  }

  f32x16 acc[4];
#pragma unroll
  for (int cb = 0; cb < 4; ++cb)
#pragma unroll
    for (int r = 0; r < 16; ++r) acc[cb][r] = 0.0f;
  float m_r[16], l_r[16];
#pragma unroll
  for (int r = 0; r < 16; ++r) { m_r[r] = -1e30f; l_r[r] = 0.0f; }

  const float* Kb = K + ((size_t)b * Dseq) * Dk;
  const float* Vb = V + ((size_t)b * Dseq) * Dk;

  for (int t = 0; t < NTILES; ++t) {
    const int kb = kb0 + t * 32;

    // ---- S = (Q*scale) · K^T   [32 q, 32 keys]
    bf16x8 kf[8];
    {
      const float* krow = Kb + (size_t)(kb + c32) * Dk + hi * 8;
#pragma unroll
      for (int s = 0; s < 8; ++s) {
        float4 a = *(const float4*)(krow + s * 16);
        float4 b4 = *(const float4*)(krow + s * 16 + 4);
        kf[s] = cvt8(a, b4);
      }
    }
    f32x16 S;
#pragma unroll
    for (int r = 0; r < 16; ++r) S[r] = 0.0f;
#pragma unroll
    for (int s = 0; s < 8; ++s)
      S = __builtin_amdgcn_mfma_f32_32x32x16_bf16(qa[s], kf[s], S, 0, 0, 0);

    // ---- V B-fragments (scalar but fully coalesced: lanes 0..31 read 128B
    //      contiguous of one V row)
    bf16x8 vf[4][2];
    {
      const float* vbase = Vb + (size_t)(kb + hi * 8) * Dk + c32;
#pragma unroll
      for (int cb = 0; cb < 4; ++cb)
#pragma unroll
        for (int s2 = 0; s2 < 2; ++s2)
#pragma unroll
          for (int j = 0; j < 8; ++j)
            vf[cb][s2][j] = f2bf(vbase[(size_t)(s2 * 16 + j) * Dk + cb * 32]);
    }

    // ---- online softmax over this 32-key tile
    float tm[16];
#pragma unroll
    for (int r = 0; r < 16; ++r) tm[r] = S[r];
#pragma unroll
    for (int off = 1; off <= 16; off <<= 1)
#pragma unroll
      for (int r = 0; r < 16; ++r)
        tm[r] = fmaxf(tm[r], __shfl_xor(tm[r], off, 64));

    float p_[16], sf[16];
#pragma unroll
    for (int r = 0; r < 16; ++r) {
      float mn = fmaxf(m_r[r], tm[r]);
      sf[r] = __expf(m_r[r] - mn);
      p_[r] = __expf(S[r] - mn);
      m_r[r] = mn;
    }
    float rs[16];
#pragma unroll
    for (int r = 0; r < 16; ++r) rs[r] = p_[r];
#pragma unroll
    for (int off = 1; off <= 16; off <<= 1)
#pragma unroll
      for (int r = 0; r < 16; ++r)
        rs[r] += __shfl_xor(rs[r], off, 64);
#pragma unroll
    for (int r = 0; r < 16; ++r) l_r[r] = l_r[r] * sf[r] + rs[r];
#pragma unroll
    for (int cb = 0; cb < 4; ++cb)
#pragma unroll
      for (int r = 0; r < 16; ++r) acc[cb][r] *= sf[r];

    // ---- P: C-layout -> A-layout via per-wave LDS tile (same-wave, no barrier)
#pragma unroll
    for (int r = 0; r < 16; ++r) {
      const int row = (r & 3) + 8 * (r >> 2) + 4 * hi;
      p_lds[w][row][c32] = f2bf(p_[r]);
    }
    bf16x8 pa[2];
    pa[0] = *(const bf16x8*)&p_lds[w][c32][hi * 8];
    pa[1] = *(const bf16x8*)&p_lds[w][c32][16 + hi * 8];

    // ---- O += P · V
#pragma unroll
    for (int cb = 0; cb < 4; ++cb)
#pragma unroll
      for (int s2 = 0; s2 < 2; ++s2)
        acc[cb] = __builtin_amdgcn_mfma_f32_32x32x16_bf16(pa[s2], vf[cb][s2],
                                                          acc[cb], 0, 0, 0);
  }

  // ---- merge the 4 waves' (m, l, O) into one per-WG partial
  __syncthreads();
  if (c32 == 0) {
#pragma unroll
    for (int r = 0; r < 16; ++r) {
      const int row = (r & 3) + 8 * (r >> 2) + 4 * hi;
      m_lds[w][row] = m_r[r];
      l_lds[w][row] = l_r[r];
    }
  }
  __syncthreads();

  float fw[16];
#pragma unroll
  for (int r = 0; r < 16; ++r) {
    const int row = (r & 3) + 8 * (r >> 2) + 4 * hi;
    float M = fmaxf(fmaxf(m_lds[0][row], m_lds[1][row]),
                    fmaxf(m_lds[2][row], m_lds[3][row]));
    fw[r] = __expf(m_r[r] - M);
  }

#pragma unroll
  for (int ww = 0; ww < 4; ++ww) {
    if (w == ww) {
#pragma unroll
      for (int cb = 0; cb < 4; ++cb)
#pragma unroll
        for (int r = 0; r < 16; ++r) {
          const int row = (r & 3) + 8 * (r >> 2) + 4 * hi;
          const float val = acc[cb][r] * fw[r];
          if (ww == 0) o_lds[row][cb * 32 + c32] = val;
          else         o_lds[row][cb * 32 + c32] += val;
        }
    }
    __syncthreads();
  }

  float* oo = ows + (size_t)wg * (32 * 128);
#pragma unroll
  for (int i = 0; i < 16; ++i) {
    const int e = tid + 256 * i;
    oo[e] = o_lds[e >> 7][e & 127];
  }
  if (tid < 32) {
    const float M = fmaxf(fmaxf(m_lds[0][tid], m_lds[1][tid]),
                          fmaxf(m_lds[2][tid], m_lds[3][tid]));
    float L = 0.0f;
#pragma unroll
    for (int ww = 0; ww < 4; ++ww)
      L += l_lds[ww][tid] * __expf(m_lds[ww][tid] - M);
    mws[wg * 32 + tid] = M;
    lws[wg * 32 + tid] = L;
  }
}

// Combine NSPLIT partials per (b, q) row.
template <int NSPLIT>
__global__ void attn_combine(const float* __restrict__ ows,
                             const float* __restrict__ mws,
                             const float* __restrict__ lws,
                             float* __restrict__ out) {
  const int bq = blockIdx.x;       // b*32 + q
  const int v = threadIdx.x;       // 0..127
  const int b = bq >> 5;
  const int qrow = bq & 31;
  const int slot0 = b * NSPLIT;

  float M = -1e30f;
#pragma unroll
  for (int c = 0; c < NSPLIT; ++c)
    M = fmaxf(M, mws[(slot0 + c) * 32 + qrow]);

  float acc = 0.0f, L = 0.0f;
#pragma unroll
  for (int c = 0; c < NSPLIT; ++c) {
    const float f = __expf(mws[(slot0 + c) * 32 + qrow] - M);
    L += lws[(slot0 + c) * 32 + qrow] * f;
    acc += f * ows[(size_t)(slot0 + c) * 4096 + qrow * 128 + v];
  }
  out[(size_t)bq * 128 + v] = acc / L;
}

extern "C" void kernel_launch(void* const* d_in, const int* in_sizes, int n_in,
                              void* d_out, int out_size, void* d_ws, size_t ws_size,
                              hipStream_t stream) {
  const float* Q = (const float*)d_in[0];
  const float* K = (const float*)d_in[1];
  const float* V = (const float*)d_in[2];
  float* out = (float*)d_out;

  // Workspace need for NSPLIT splits: 32*NSPLIT*(4096 + 64) floats.
  const size_t need32 = (size_t)32 * 32 * (4096 + 64) * sizeof(float);  // ~17 MB

  if (ws_size >= need32) {
    constexpr int NS = 32;
    float* ows = (float*)d_ws;
    float* mws = ows + (size_t)32 * NS * 4096;
    float* lws = mws + (size_t)32 * NS * 32;
    attn_partial<NS><<<32 * NS, 256, 0, stream>>>(Q, K, V, ows, mws, lws);
    attn_combine<NS><<<32 * 32, 128, 0, stream>>>(ows, mws, lws, out);
  } else {
    constexpr int NS = 16;
    float* ows = (float*)d_ws;
    float* mws = ows + (size_t)32 * NS * 4096;
    float* lws = mws + (size_t)32 * NS * 32;
    attn_partial<NS><<<32 * NS, 256, 0, stream>>>(Q, K, V, ows, mws, lws);
    attn_combine<NS><<<32 * 32, 128, 0, stream>>>(ows, mws, lws, out);
  }
}

// Round 4
// 87.304 us; speedup vs baseline: 2.0804x; 2.0804x over previous
//
#include <hip/hip_runtime.h>
#include <hip/hip_bf16.h>

// Attention: out[b,q,v] = softmax_d( Q[q,:]·K[b,d,:] / sqrt(128) ) · V[b,d,v]
// B=32, D=8192, DK=DV=128. fp32 in/out, bf16 MFMA internally.
// R3: latency fix. Cooperative 32-key tiles per block (4 waves), V double-
//     buffered in LDS via global_load_lds, K register-prefetched 1 tile ahead.
//     Swapped-operand QK^T (S^T) -> in-register softmax (per-lane q state);
//     swapped PV (O^T) via cvt_pk_bf16 + permlane32_swap. No cross-wave merge.

#define NSPLIT 16
#define Dseq 8192
#define Dk 128
#define KT 32
#define NT (Dseq / NSPLIT / KT)   // 16 tiles per block

typedef __attribute__((ext_vector_type(8))) short bf16x8;
typedef __attribute__((ext_vector_type(16))) float f32x16;

__device__ __forceinline__ unsigned cvt_pk(float lo, float hi) {
  unsigned d;
  asm("v_cvt_pk_bf16_f32 %0, %1, %2" : "=v"(d) : "v"(lo), "v"(hi));
  return d;
}
__device__ __forceinline__ void plane32_swap(unsigned& a, unsigned& b) {
  // vdst.hi <-> vsrc.lo : out a = {a.lo, b.lo}, out b = {a.hi, b.hi}
  asm volatile("v_permlane32_swap_b32 %0, %1" : "+v"(a), "+v"(b));
}

union frag_u { unsigned u[4]; bf16x8 v; };

// mfma_f32_32x32x16_bf16 layouts (m74/m101 verified):
//  A[32,16]: lane l -> row = l&31, k = (l>>5)*8 + j
//  B[16,32]: lane l -> col = l&31, k = (l>>5)*8 + j
//  C/D     : lane l -> col = l&31, row = (r&3) + 8*(r>>2) + 4*(l>>5)

__global__ __launch_bounds__(256, 2) void attn_partial(
    const float* __restrict__ Q, const float* __restrict__ K,
    const float* __restrict__ V, float* __restrict__ ows,
    float* __restrict__ mws, float* __restrict__ lws) {
  // smem: V double buffer 2*16KB; epilogue O-transpose overlays it.
  __shared__ alignas(16) float smem[2 * KT * Dk];

  const int tid = threadIdx.x;
  const int lane = tid & 63;
  const int w = tid >> 6;          // wave 0..3, owns V cols [32w,32w+32)
  const int c32 = lane & 31;
  const int hi = lane >> 5;
  const int wg = blockIdx.x;
  const int b = wg >> 4;           // NSPLIT=16
  const int kb0 = (wg & 15) * (Dseq / NSPLIT);

  const float scale = 0.088388347648318447f;  // 1/sqrt(128)

  // ---- Q as B-fragment (lane: q=c32, k=hi*8+j+16s), prescaled, resident
  bf16x8 qa[8];
  {
    const float* qrow = Q + c32 * Dk + hi * 8;
#pragma unroll
    for (int s = 0; s < 8; ++s) {
      float4 a = *(const float4*)(qrow + s * 16);
      float4 b4 = *(const float4*)(qrow + s * 16 + 4);
      frag_u f;
      f.u[0] = cvt_pk(a.x * scale, a.y * scale);
      f.u[1] = cvt_pk(a.z * scale, a.w * scale);
      f.u[2] = cvt_pk(b4.x * scale, b4.y * scale);
      f.u[3] = cvt_pk(b4.z * scale, b4.w * scale);
      qa[s] = f.v;
    }
  }

  const float* Kb = K + (size_t)b * Dseq * Dk;
  const char* Vb = (const char*)(V + (size_t)b * Dseq * Dk);

  // V staging: 16KB tile, 4 chunks x (256 thr * 16B). Wave-uniform LDS dest.
  auto stageV = [&](int buf, int kb) {
#pragma unroll
    for (int c = 0; c < 4; ++c) {
      const char* src = Vb + (size_t)kb * 512 + c * 4096 + w * 1024 + lane * 16;
      char* dst = (char*)smem + buf * 16384 + c * 4096 + w * 1024;
      __builtin_amdgcn_global_load_lds(
          (const __attribute__((address_space(1))) void*)src,
          (__attribute__((address_space(3))) void*)dst, 16, 0, 0);
    }
  };

  // K prefetch regs (A-frag source): lane row = key kb+c32, bytes hi*32+64s
  float4 ka[8], kb4[8];
  auto loadK = [&](int kb) {
    const float* krow = Kb + (size_t)(kb + c32) * Dk + hi * 8;
#pragma unroll
    for (int s = 0; s < 8; ++s) {
      ka[s] = *(const float4*)(krow + s * 16);
      kb4[s] = *(const float4*)(krow + s * 16 + 4);
    }
  };

  f32x16 acc;
#pragma unroll
  for (int r = 0; r < 16; ++r) acc[r] = 0.0f;
  float m_r = -1e30f, l_r = 0.0f;

  // ---- prologue
  stageV(0, kb0);
  loadK(kb0);
  __syncthreads();

  for (int t = 0; t < NT; ++t) {
    const int buf = t & 1;

    // 1) convert current K regs -> A-fragments (frees the f32 regs)
    frag_u kf[8];
#pragma unroll
    for (int s = 0; s < 8; ++s) {
      kf[s].u[0] = cvt_pk(ka[s].x, ka[s].y);
      kf[s].u[1] = cvt_pk(ka[s].z, ka[s].w);
      kf[s].u[2] = cvt_pk(kb4[s].x, kb4[s].y);
      kf[s].u[3] = cvt_pk(kb4[s].z, kb4[s].w);
    }

    // 2) issue next tile's loads NOW (overlap with compute below)
    if (t + 1 < NT) {
      loadK(kb0 + (t + 1) * KT);
      stageV(buf ^ 1, kb0 + (t + 1) * KT);
    }
    __builtin_amdgcn_sched_barrier(0);  // don't let loads sink below compute

    // 3) S^T[key,q] = mfma(A=K, B=Q): lane q=c32, regs = keys crow(r,hi)
    f32x16 S;
#pragma unroll
    for (int r = 0; r < 16; ++r) S[r] = 0.0f;
#pragma unroll
    for (int s = 0; s < 8; ++s)
      S = __builtin_amdgcn_mfma_f32_32x32x16_bf16(kf[s].v, qa[s], S, 0, 0, 0);

    // 4) online softmax, fully in-register (per-lane q; 16 keys/lane + xhalf)
    float tmax = S[0];
#pragma unroll
    for (int r = 1; r < 16; ++r) tmax = fmaxf(tmax, S[r]);
    tmax = fmaxf(tmax, __shfl_xor(tmax, 32, 64));
    const float mn = fmaxf(m_r, tmax);
    const float sf = __expf(m_r - mn);
    m_r = mn;
    float p[16];
#pragma unroll
    for (int r = 0; r < 16; ++r) p[r] = __expf(S[r] - mn);
    float rs = p[0];
#pragma unroll
    for (int r = 1; r < 16; ++r) rs += p[r];
    rs += __shfl_xor(rs, 32, 64);
    l_r = l_r * sf + rs;
#pragma unroll
    for (int r = 0; r < 16; ++r) acc[r] *= sf;

    // 5) P^T -> B-fragments via cvt_pk + permlane32_swap (no LDS, no barrier)
    //    pair i -> keys (4hi + base): i0:(0,1) i1:(2,3) i2:(8,9) i3:(10,11)
    //                                 i4:(16,17) i5:(18,19) i6:(24,25) i7:(26,27)
    unsigned a0 = cvt_pk(p[0], p[1]),  a1 = cvt_pk(p[2], p[3]);
    unsigned a2 = cvt_pk(p[4], p[5]),  a3 = cvt_pk(p[6], p[7]);
    unsigned a4 = cvt_pk(p[8], p[9]),  a5 = cvt_pk(p[10], p[11]);
    unsigned a6 = cvt_pk(p[12], p[13]), a7 = cvt_pk(p[14], p[15]);
    plane32_swap(a0, a2);  // -> pa0.d0, pa0.d2
    plane32_swap(a1, a3);  // -> pa0.d1, pa0.d3
    plane32_swap(a4, a6);  // -> pa1.d0, pa1.d2
    plane32_swap(a5, a7);  // -> pa1.d1, pa1.d3
    frag_u pa0, pa1;
    pa0.u[0] = a0; pa0.u[1] = a1; pa0.u[2] = a2; pa0.u[3] = a3;
    pa1.u[0] = a4; pa1.u[1] = a5; pa1.u[2] = a6; pa1.u[3] = a7;

    // 6) V^T A-fragments from LDS (bank-clean: lanes hit distinct banks)
    const float* Vt = smem + buf * 4096;
    frag_u vf[2];
#pragma unroll
    for (int s2 = 0; s2 < 2; ++s2) {
      float e[8];
#pragma unroll
      for (int j = 0; j < 8; ++j)
        e[j] = Vt[(hi * 8 + j + 16 * s2) * Dk + 32 * w + c32];
      vf[s2].u[0] = cvt_pk(e[0], e[1]);
      vf[s2].u[1] = cvt_pk(e[2], e[3]);
      vf[s2].u[2] = cvt_pk(e[4], e[5]);
      vf[s2].u[3] = cvt_pk(e[6], e[7]);
    }

    // 7) O^T[v,q] += mfma(A=V^T, B=P^T)
    acc = __builtin_amdgcn_mfma_f32_32x32x16_bf16(vf[0].v, pa0.v, acc, 0, 0, 0);
    acc = __builtin_amdgcn_mfma_f32_32x32x16_bf16(vf[1].v, pa1.v, acc, 0, 0, 0);

    // 8) barrier: drains staged V + prefetched K (they had the whole compute
    //    window); protects buf swap.
    __syncthreads();
  }

  // ---- epilogue: O^T -> o_lds transpose (overlays V buffers) -> coalesced st
  float* ol = (float*)smem;  // [128][33]
#pragma unroll
  for (int r = 0; r < 16; ++r) {
    const int vv = 32 * w + (r & 3) + 8 * (r >> 2) + 4 * hi;
    ol[vv * 33 + c32] = acc[r];
  }
  __syncthreads();
  {
    float* oo = ows + (size_t)wg * 4096;
    const int q = tid >> 3;
    const int v0 = (tid & 7) * 16;
#pragma unroll
    for (int g = 0; g < 4; ++g) {
      float4 s;
      s.x = ol[(v0 + 4 * g + 0) * 33 + q];
      s.y = ol[(v0 + 4 * g + 1) * 33 + q];
      s.z = ol[(v0 + 4 * g + 2) * 33 + q];
      s.w = ol[(v0 + 4 * g + 3) * 33 + q];
      *(float4*)(oo + q * 128 + v0 + 4 * g) = s;
    }
  }
  if (w == 0 && hi == 0) {
    mws[wg * 32 + c32] = m_r;
    lws[wg * 32 + c32] = l_r;
  }
}

// Combine NSPLIT partials per (b, q) row.
__global__ void attn_combine(const float* __restrict__ ows,
                             const float* __restrict__ mws,
                             const float* __restrict__ lws,
                             float* __restrict__ out) {
  const int bq = blockIdx.x;       // b*32 + q
  const int v = threadIdx.x;       // 0..127
  const int b = bq >> 5;
  const int qrow = bq & 31;
  const int slot0 = b * NSPLIT;

  float M = -1e30f;
#pragma unroll
  for (int c = 0; c < NSPLIT; ++c)
    M = fmaxf(M, mws[(slot0 + c) * 32 + qrow]);

  float acc = 0.0f, L = 0.0f;
#pragma unroll
  for (int c = 0; c < NSPLIT; ++c) {
    const float f = __expf(mws[(slot0 + c) * 32 + qrow] - M);
    L += lws[(slot0 + c) * 32 + qrow] * f;
    acc += f * ows[(size_t)(slot0 + c) * 4096 + qrow * 128 + v];
  }
  out[(size_t)bq * 128 + v] = acc / L;
}

extern "C" void kernel_launch(void* const* d_in, const int* in_sizes, int n_in,
                              void* d_out, int out_size, void* d_ws, size_t ws_size,
                              hipStream_t stream) {
  const float* Q = (const float*)d_in[0];
  const float* K = (const float*)d_in[1];
  const float* V = (const float*)d_in[2];
  float* out = (float*)d_out;

  float* ows = (float*)d_ws;                        // 512 * 4096 f32 = 8 MB
  float* mws = ows + (size_t)32 * NSPLIT * 4096;    // 512 * 32 f32
  float* lws = mws + (size_t)32 * NSPLIT * 32;      // 512 * 32 f32

  attn_partial<<<32 * NSPLIT, 256, 0, stream>>>(Q, K, V, ows, mws, lws);
  attn_combine<<<32 * 32, 128, 0, stream>>>(ows, mws, lws, out);
}

// Round 5
// 55.652 us; speedup vs baseline: 3.2636x; 1.5687x over previous
//
#include <hip/hip_runtime.h>
#include <hip/hip_bf16.h>

// Attention: out[b,q,v] = softmax_d( Q[q,:]·K[b,d,:] / sqrt(128) ) · V[b,d,v]
// B=32, D=8192, DK=DV=128. fp32 in/out, bf16 MFMA internally.
// R4: issue-BW fix. R3 issued 80KB/block-iter (K 4x redundant) and sat at the
//     ~10B/cyc/CU vector-memory ceiling. Now: K staged ONCE per block into LDS
//     as bf16 (reg-staged, XOR-swizzled both sides), V per-wave direct global
//     (unique). 32KB/block-iter = minimal. Single barrier/iter (K dbuf).

#define NSPLIT 16
#define Dseq 8192
#define Dk 128
#define KT 32
#define NT (Dseq / NSPLIT / KT)   // 16 tiles per block

typedef __attribute__((ext_vector_type(8))) short bf16x8;
typedef __attribute__((ext_vector_type(16))) float f32x16;

__device__ __forceinline__ unsigned cvt_pk(float lo, float hi) {
  unsigned d;
  asm("v_cvt_pk_bf16_f32 %0, %1, %2" : "=v"(d) : "v"(lo), "v"(hi));
  return d;
}
__device__ __forceinline__ void plane32_swap(unsigned& a, unsigned& b) {
  // out a = {a.lo, b.lo}, out b = {a.hi, b.hi} across lane<32/lane>=32
  asm volatile("v_permlane32_swap_b32 %0, %1" : "+v"(a), "+v"(b));
}

union frag_u { unsigned u[4]; bf16x8 v; };

// mfma_f32_32x32x16_bf16 layouts (m74/m101 verified):
//  A[32,16]: lane l -> row = l&31, k = (l>>5)*8 + j
//  B[16,32]: lane l -> col = l&31, k = (l>>5)*8 + j
//  C/D     : lane l -> col = l&31, row = (r&3) + 8*(r>>2) + 4*(l>>5)

__global__ __launch_bounds__(256, 2) void attn_partial(
    const float* __restrict__ Q, const float* __restrict__ K,
    const float* __restrict__ V, float* __restrict__ ows,
    float* __restrict__ mws, float* __restrict__ lws) {
  // 16.9 KB: epilogue transpose [128][33]; K bf16 double-buffer (2x8KB)
  // overlays the first 16 KB during the main loop.
  __shared__ alignas(16) float smem[128 * 33];
  char* kls = (char*)smem;

  const int tid = threadIdx.x;
  const int lane = tid & 63;
  const int w = tid >> 6;          // wave 0..3, owns V cols [32w, 32w+32)
  const int c32 = lane & 31;
  const int hi = lane >> 5;
  const int wg = blockIdx.x;
  const int b = wg >> 4;           // NSPLIT=16
  const int kb0 = (wg & 15) * (Dseq / NSPLIT);

  const float scale = 0.088388347648318447f;  // 1/sqrt(128)

  // K staging geometry: wave w owns tile rows [8w, 8w+8); lane covers
  // row 8w+(lane>>3), f32 cols (lane&7)*16 .. +15.
  const int krow_l = 8 * w + (lane >> 3);
  const int kcol0 = (lane & 7) * 16;
  const int ksw = (krow_l & 7) << 4;                  // write-side XOR
  const int ko0 = krow_l * 256 + (lane & 7) * 32;     // tile-local byte

  // ---- Q as B-fragment (q = c32, k = hi*8 + j + 16s), prescaled, resident
  bf16x8 qa[8];
  {
    const float* qrow = Q + c32 * Dk + hi * 8;
#pragma unroll
    for (int s = 0; s < 8; ++s) {
      float4 a = *(const float4*)(qrow + s * 16);
      float4 b4 = *(const float4*)(qrow + s * 16 + 4);
      frag_u f;
      f.u[0] = cvt_pk(a.x * scale, a.y * scale);
      f.u[1] = cvt_pk(a.z * scale, a.w * scale);
      f.u[2] = cvt_pk(b4.x * scale, b4.y * scale);
      f.u[3] = cvt_pk(b4.z * scale, b4.w * scale);
      qa[s] = f.v;
    }
  }

  const float* Kb = K + (size_t)b * Dseq * Dk;
  const float* Vb = V + (size_t)b * Dseq * Dk;

  f32x16 acc;
#pragma unroll
  for (int r = 0; r < 16; ++r) acc[r] = 0.0f;
  float m_r = -1e30f, l_r = 0.0f;

  // ---- prologue: stage K tile 0 into buf 0 (bf16, swizzled)
  {
    const float* src = Kb + (size_t)(kb0 + krow_l) * Dk + kcol0;
    float4 k0 = *(const float4*)(src);
    float4 k1 = *(const float4*)(src + 4);
    float4 k2 = *(const float4*)(src + 8);
    float4 k3 = *(const float4*)(src + 12);
    frag_u lo, hi4;
    lo.u[0] = cvt_pk(k0.x, k0.y);  lo.u[1] = cvt_pk(k0.z, k0.w);
    lo.u[2] = cvt_pk(k1.x, k1.y);  lo.u[3] = cvt_pk(k1.z, k1.w);
    hi4.u[0] = cvt_pk(k2.x, k2.y); hi4.u[1] = cvt_pk(k2.z, k2.w);
    hi4.u[2] = cvt_pk(k3.x, k3.y); hi4.u[3] = cvt_pk(k3.z, k3.w);
    *(bf16x8*)(kls + (ko0 ^ ksw)) = lo.v;
    *(bf16x8*)(kls + ((ko0 + 16) ^ ksw)) = hi4.v;
  }
  __syncthreads();

  for (int t = 0; t < NT; ++t) {
    const int kb = kb0 + t * KT;

    // A) issue V(t) loads (unique per wave: its 32 v-cols x 32 keys, 4KB)
    float vr[16];
    {
      const float* vsrc = Vb + (size_t)(kb + hi * 8) * Dk + 32 * w + c32;
#pragma unroll
      for (int s2 = 0; s2 < 2; ++s2)
#pragma unroll
        for (int j = 0; j < 8; ++j)
          vr[s2 * 8 + j] = vsrc[(size_t)(16 * s2 + j) * Dk];
    }

    // B) issue K(t+1) loads (cooperative: wave's 8 rows, 4KB)
    float4 kr0, kr1, kr2, kr3;
    if (t + 1 < NT) {
      const float* src = Kb + (size_t)(kb + KT + krow_l) * Dk + kcol0;
      kr0 = *(const float4*)(src);
      kr1 = *(const float4*)(src + 4);
      kr2 = *(const float4*)(src + 8);
      kr3 = *(const float4*)(src + 12);
    }
    __builtin_amdgcn_sched_barrier(0);  // keep load issues above compute

    // C) K fragments from LDS buf[t&1] (swizzled, conflict-free b128)
    const char* kbase = kls + (t & 1) * 8192;
    bf16x8 kf[8];
#pragma unroll
    for (int s = 0; s < 8; ++s) {
      const int o = (c32 * 256 + hi * 16 + s * 32) ^ ((c32 & 7) << 4);
      kf[s] = *(const bf16x8*)(kbase + o);
    }

    // D) S^T[key,q] = mfma(A=K, B=Q): lane q=c32, regs = keys crow(r,hi)
    f32x16 S;
#pragma unroll
    for (int r = 0; r < 16; ++r) S[r] = 0.0f;
#pragma unroll
    for (int s = 0; s < 8; ++s)
      S = __builtin_amdgcn_mfma_f32_32x32x16_bf16(kf[s], qa[s], S, 0, 0, 0);

    // E) online softmax, in-register (per-lane q; 16 keys/lane + xhalf)
    float tmax = S[0];
#pragma unroll
    for (int r = 1; r < 16; ++r) tmax = fmaxf(tmax, S[r]);
    tmax = fmaxf(tmax, __shfl_xor(tmax, 32, 64));
    const float mn = fmaxf(m_r, tmax);
    const float sf = __expf(m_r - mn);
    m_r = mn;
    float p[16];
#pragma unroll
    for (int r = 0; r < 16; ++r) p[r] = __expf(S[r] - mn);
    float rs = p[0];
#pragma unroll
    for (int r = 1; r < 16; ++r) rs += p[r];
    rs += __shfl_xor(rs, 32, 64);
    l_r = l_r * sf + rs;
#pragma unroll
    for (int r = 0; r < 16; ++r) acc[r] *= sf;

    // F) P^T -> B-fragments via cvt_pk + permlane32_swap
    unsigned a0 = cvt_pk(p[0], p[1]),   a1 = cvt_pk(p[2], p[3]);
    unsigned a2 = cvt_pk(p[4], p[5]),   a3 = cvt_pk(p[6], p[7]);
    unsigned a4 = cvt_pk(p[8], p[9]),   a5 = cvt_pk(p[10], p[11]);
    unsigned a6 = cvt_pk(p[12], p[13]), a7 = cvt_pk(p[14], p[15]);
    plane32_swap(a0, a2);
    plane32_swap(a1, a3);
    plane32_swap(a4, a6);
    plane32_swap(a5, a7);
    frag_u pa0, pa1;
    pa0.u[0] = a0; pa0.u[1] = a1; pa0.u[2] = a2; pa0.u[3] = a3;
    pa1.u[0] = a4; pa1.u[1] = a5; pa1.u[2] = a6; pa1.u[3] = a7;

    // G) V fragments from the prefetched regs; O^T += mfma(A=V^T, B=P^T)
    frag_u vf0, vf1;
    vf0.u[0] = cvt_pk(vr[0], vr[1]);   vf0.u[1] = cvt_pk(vr[2], vr[3]);
    vf0.u[2] = cvt_pk(vr[4], vr[5]);   vf0.u[3] = cvt_pk(vr[6], vr[7]);
    vf1.u[0] = cvt_pk(vr[8], vr[9]);   vf1.u[1] = cvt_pk(vr[10], vr[11]);
    vf1.u[2] = cvt_pk(vr[12], vr[13]); vf1.u[3] = cvt_pk(vr[14], vr[15]);
    acc = __builtin_amdgcn_mfma_f32_32x32x16_bf16(vf0.v, pa0.v, acc, 0, 0, 0);
    acc = __builtin_amdgcn_mfma_f32_32x32x16_bf16(vf1.v, pa1.v, acc, 0, 0, 0);

    // H) stage K(t+1) into buf[(t+1)&1] (loads had the whole compute window)
    if (t + 1 < NT) {
      frag_u lo, hi4;
      lo.u[0] = cvt_pk(kr0.x, kr0.y);  lo.u[1] = cvt_pk(kr0.z, kr0.w);
      lo.u[2] = cvt_pk(kr1.x, kr1.y);  lo.u[3] = cvt_pk(kr1.z, kr1.w);
      hi4.u[0] = cvt_pk(kr2.x, kr2.y); hi4.u[1] = cvt_pk(kr2.z, kr2.w);
      hi4.u[2] = cvt_pk(kr3.x, kr3.y); hi4.u[3] = cvt_pk(kr3.z, kr3.w);
      char* wbase = kls + ((t + 1) & 1) * 8192;
      *(bf16x8*)(wbase + (ko0 ^ ksw)) = lo.v;
      *(bf16x8*)(wbase + ((ko0 + 16) ^ ksw)) = hi4.v;
    }
    __syncthreads();
  }

  // ---- epilogue: O^T -> smem transpose -> coalesced partial store
  float* ol = smem;  // [128][33]
#pragma unroll
  for (int r = 0; r < 16; ++r) {
    const int vv = 32 * w + (r & 3) + 8 * (r >> 2) + 4 * hi;
    ol[vv * 33 + c32] = acc[r];
  }
  __syncthreads();
  {
    float* oo = ows + (size_t)wg * 4096;
    const int q = tid >> 3;
    const int v0 = (tid & 7) * 16;
#pragma unroll
    for (int g = 0; g < 4; ++g) {
      float4 s;
      s.x = ol[(v0 + 4 * g + 0) * 33 + q];
      s.y = ol[(v0 + 4 * g + 1) * 33 + q];
      s.z = ol[(v0 + 4 * g + 2) * 33 + q];
      s.w = ol[(v0 + 4 * g + 3) * 33 + q];
      *(float4*)(oo + q * 128 + v0 + 4 * g) = s;
    }
  }
  if (w == 0 && hi == 0) {
    mws[wg * 32 + c32] = m_r;
    lws[wg * 32 + c32] = l_r;
  }
}

// Combine NSPLIT partials per (b, q) row.
__global__ void attn_combine(const float* __restrict__ ows,
                             const float* __restrict__ mws,
                             const float* __restrict__ lws,
                             float* __restrict__ out) {
  const int bq = blockIdx.x;       // b*32 + q
  const int v = threadIdx.x;       // 0..127
  const int b = bq >> 5;
  const int qrow = bq & 31;
  const int slot0 = b * NSPLIT;

  float M = -1e30f;
#pragma unroll
  for (int c = 0; c < NSPLIT; ++c)
    M = fmaxf(M, mws[(slot0 + c) * 32 + qrow]);

  float acc = 0.0f, L = 0.0f;
#pragma unroll
  for (int c = 0; c < NSPLIT; ++c) {
    const float f = __expf(mws[(slot0 + c) * 32 + qrow] - M);
    L += lws[(slot0 + c) * 32 + qrow] * f;
    acc += f * ows[(size_t)(slot0 + c) * 4096 + qrow * 128 + v];
  }
  out[(size_t)bq * 128 + v] = acc / L;
}

extern "C" void kernel_launch(void* const* d_in, const int* in_sizes, int n_in,
                              void* d_out, int out_size, void* d_ws, size_t ws_size,
                              hipStream_t stream) {
  const float* Q = (const float*)d_in[0];
  const float* K = (const float*)d_in[1];
  const float* V = (const float*)d_in[2];
  float* out = (float*)d_out;

  float* ows = (float*)d_ws;                        // 512 * 4096 f32 = 8 MB
  float* mws = ows + (size_t)32 * NSPLIT * 4096;    // 512 * 32 f32
  float* lws = mws + (size_t)32 * NSPLIT * 32;      // 512 * 32 f32

  attn_partial<<<32 * NSPLIT, 256, 0, stream>>>(Q, K, V, ows, mws, lws);
  attn_combine<<<32 * 32, 128, 0, stream>>>(ows, mws, lws, out);
}